// Round 4
// baseline (210.654 us; speedup 1.0000x reference)
//
#include <hip/hip_runtime.h>
#include <hip/hip_bf16.h>
#include <stdint.h>

// B=2, T=2048, E=1024, H=16, D=64. q=x@Wq^T etc., T5 bias, causal softmax, out=(PV)@Wo^T.

typedef __attribute__((ext_vector_type(8))) short bf16x8;   // 8 bf16 = 4 VGPR (MFMA A/B frag)
typedef __attribute__((ext_vector_type(4))) float f32x4;    // MFMA C/D frag

#define MFMA16(a, b, c) __builtin_amdgcn_mfma_f32_16x16x32_bf16((a), (b), (c), 0, 0, 0)

typedef __attribute__((address_space(1))) void gvoid_t;
typedef __attribute__((address_space(3))) void lvoid_t;

// async global->LDS, 16B/lane; LDS dest is wave-uniform base + lane*16
__device__ __forceinline__ void gload16(const void* g, void* l) {
    __builtin_amdgcn_global_load_lds((gvoid_t*)g, (lvoid_t*)l, 16, 0, 0);
}

__device__ __forceinline__ ushort f2bf_rne(float f) {
    union { float f; uint32_t u; } v; v.f = f;
    uint32_t u = v.u;
    return (ushort)((u + 0x7FFFu + ((u >> 16) & 1u)) >> 16);
}

// ---------------- fused fp32->bf16: x (4M) + Wq/Wk/Wv/Wo (1M each) -> ws[0..8M) ----------
__global__ void cvt_all(const float* __restrict__ x,
                        const float* __restrict__ wq, const float* __restrict__ wk,
                        const float* __restrict__ wv, const float* __restrict__ wo,
                        ushort* __restrict__ out) {
    int i = (blockIdx.x * 256 + threadIdx.x) * 4;           // [0, 8M)
    int sel = i >> 20;
    const float* src; int off;
    if (sel < 4) { src = x; off = i; }
    else {
        src = (sel == 4) ? wq : (sel == 5) ? wk : (sel == 6) ? wv : wo;
        off = i & 1048575;
    }
    float4 f = *(const float4*)(src + off);
    ushort4 o;
    o.x = f2bf_rne(f.x); o.y = f2bf_rne(f.y);
    o.z = f2bf_rne(f.z); o.w = f2bf_rne(f.w);
    *(ushort4*)(out + i) = o;
}

// ---------------- T5 bias table: bias_tab[h][rel], rel in [0,2048) ----------------
// exact integer thresholds: bucket t>=n iff rel >= {8,12,16,23,32,46,64,91}[n]
__global__ void build_bias(const float* __restrict__ rel_emb, float* __restrict__ bias_tab) {
    int idx = blockIdx.x * 256 + threadIdx.x;       // 16*2048
    int h = idx >> 11, rel = idx & 2047;
    int bucket;
    if (rel == 0) bucket = 0;
    else if (rel < 8) bucket = 16 + rel;
    else {
        int t;
        if      (rel >= 91) t = 7;
        else if (rel >= 64) t = 6;
        else if (rel >= 46) t = 5;
        else if (rel >= 32) t = 4;
        else if (rel >= 23) t = 3;
        else if (rel >= 16) t = 2;
        else if (rel >= 12) t = 1;
        else                t = 0;
        bucket = 24 + t;
    }
    bias_tab[idx] = rel_emb[bucket * 16 + h];
}

// ---------------- GEMM: C[M][N] = A[M][1024] * W[N][1024]^T (bf16 in, fp32 acc) ----------
// Double-buffered LDS, 1 barrier/K-step: issue next tile's gload_lds BEFORE compute,
// end-of-iter barrier drains overlapped loads (T3-minimum recipe).
// MODE 0: BM=128, fused QKV -> q,k [B,H,T,D] bf16, V transposed [B,H,D,T] bf16
// MODE 1: BM=64 (512 blocks = 2/CU), out-proj -> fp32 d_out
template<int MODE>
__global__ __launch_bounds__(256, MODE == 0 ? 3 : 4) void gemm_bt(
    const ushort* __restrict__ A,
    const ushort* __restrict__ W0, const ushort* __restrict__ W1, const ushort* __restrict__ W2,
    ushort* __restrict__ outq, ushort* __restrict__ outk, ushort* __restrict__ outvt,
    float* __restrict__ outf)
{
    constexpr int BM  = (MODE == 0) ? 128 : 64;
    constexpr int ACH = BM / 64;                    // A chunk-sets per lane (2 or 1)
    constexpr int MI  = (MODE == 0) ? 4 : 2;        // row frags per wave
    __shared__ __align__(16) ushort lsA[2][BM * 32];
    __shared__ __align__(16) ushort lsB[2][128 * 32];
    const int tid = threadIdx.x;
    const int lane = tid & 63, w = tid >> 6;
    const int g = lane >> 4, c16 = lane & 15;
    const int m0 = blockIdx.x * BM;
    const int wm = w >> 1, wn = w & 1;

    const ushort* W;
    int n0, widx = 0;
    if (MODE == 0) {
        widx = blockIdx.y >> 3;
        W = (widx == 0) ? W0 : (widx == 1) ? W1 : W2;
        n0 = (blockIdx.y & 7) * 128;
    } else {
        W = W0;
        n0 = blockIdx.y * 128;
    }

    f32x4 acc[MI][4];
    #pragma unroll
    for (int i = 0; i < MI; i++)
        #pragma unroll
        for (int j = 0; j < 4; j++) acc[i][j] = (f32x4){0.f, 0.f, 0.f, 0.f};

    // staging chunk assignment; XOR swizzle (involution on both sides)
    int acrow[ACH], acj[ACH], bcrow[2], bcj[2];
    #pragma unroll
    for (int i = 0; i < ACH; i++) {
        int c = (i * 4 + w) * 64 + lane;
        acrow[i] = c >> 2; acj[i] = (c & 3) ^ ((acrow[i] >> 1) & 3);
    }
    #pragma unroll
    for (int i = 0; i < 2; i++) {
        int c = (i * 4 + w) * 64 + lane;
        bcrow[i] = c >> 2; bcj[i] = (c & 3) ^ ((bcrow[i] >> 1) & 3);
    }

    auto stage = [&](int buf, int kt) {
        #pragma unroll
        for (int i = 0; i < ACH; i++)
            gload16(A + (size_t)(m0 + acrow[i]) * 1024 + kt + acj[i] * 8,
                    &lsA[buf][(i * 4 + w) * 512]);
        #pragma unroll
        for (int i = 0; i < 2; i++)
            gload16(W + (size_t)(n0 + bcrow[i]) * 1024 + kt + bcj[i] * 8,
                    &lsB[buf][(i * 4 + w) * 512]);
    };

    stage(0, 0);
    __syncthreads();

    for (int it = 0; it < 32; ++it) {
        const int cur = it & 1;
        if (it < 31) stage(cur ^ 1, (it + 1) * 32);   // overlapped with compute below
        bf16x8 af[MI], bfv[4];
        #pragma unroll
        for (int mi = 0; mi < MI; mi++) {
            int row = wm * (16 * MI) + mi * 16 + c16;
            af[mi] = *(const bf16x8*)(&lsA[cur][row * 32 + ((g ^ ((row >> 1) & 3)) * 8)]);
        }
        #pragma unroll
        for (int ni = 0; ni < 4; ni++) {
            int row = wn * 64 + ni * 16 + c16;
            bfv[ni] = *(const bf16x8*)(&lsB[cur][row * 32 + ((g ^ ((row >> 1) & 3)) * 8)]);
        }
        #pragma unroll
        for (int mi = 0; mi < MI; mi++)
            #pragma unroll
            for (int ni = 0; ni < 4; ni++)
                acc[mi][ni] = MFMA16(af[mi], bfv[ni], acc[mi][ni]);
        __syncthreads();   // drains vmcnt (next-tile loads) + syncs readers
    }

    // epilogue. C/D frag: col = lane&15, row = g*4 + r (m89-verified)
    #pragma unroll
    for (int mi = 0; mi < MI; mi++) {
        #pragma unroll
        for (int ni = 0; ni < 4; ni++) {
            int mg = m0 + wm * (16 * MI) + mi * 16 + g * 4;
            if (MODE == 0) {
                int f = n0 + wn * 64 + ni * 16 + c16;     // feature in [0,1024)
                int h = f >> 6, d = f & 63;
                if (widx < 2) {
                    ushort* dst = (widx == 0) ? outq : outk;
                    #pragma unroll
                    for (int r = 0; r < 4; r++) {
                        int m = mg + r, b = m >> 11, t = m & 2047;
                        dst[((b * 16 + h) * 2048 + t) * 64 + d] = f2bf_rne(acc[mi][ni][r]);
                    }
                } else {
                    int b = mg >> 11, t = mg & 2047;      // 4 rows stay in one b
                    ushort4 pk;
                    pk.x = f2bf_rne(acc[mi][ni][0]); pk.y = f2bf_rne(acc[mi][ni][1]);
                    pk.z = f2bf_rne(acc[mi][ni][2]); pk.w = f2bf_rne(acc[mi][ni][3]);
                    *(ushort4*)(outvt + ((size_t)(b * 16 + h) * 64 + d) * 2048 + t) = pk;
                }
            } else {
                int ng = n0 + wn * 64 + ni * 16 + c16;
                #pragma unroll
                for (int r = 0; r < 4; r++) {
                    int m = mg + r;
                    outf[(size_t)m * 1024 + ng] = acc[mi][ni][r];
                }
            }
        }
    }
}

// ---------------- Flash attention (causal + T5 bias), dbuf K/V, Q in registers ----------
// 64 q-rows/block, 4 waves x 16 rows. Swapped QK^T: S^T = mfma(K, Q); softmax lane-local.
// PV as O^T = mfma(V^T, P^T), V stored [B,H,D,T]. setprio(1) around MFMA clusters (T5).
__global__ __launch_bounds__(256, 3) void attn_kernel(
    const ushort* __restrict__ qb_, const ushort* __restrict__ kb_,
    const ushort* __restrict__ vtb, const float* __restrict__ bias_tab,
    ushort* __restrict__ ob)
{
    __shared__ __align__(16) ushort KV[2][2][4096];       // [buf][K/V][64*64]
    __shared__ __align__(16) ushort Ps[4][16 * 72];       // per-wave P, padded rows

    const int tid = threadIdx.x, lane = tid & 63, w = tid >> 6;
    const int g = lane >> 4, c16 = lane & 15;
    const int bh = blockIdx.y;
    const int qb = (blockIdx.x + bh) & 31;                // work-balance swizzle
    const int b = bh >> 4, h = bh & 15;

    const ushort* qh = qb_ + (size_t)bh * 2048 * 64;
    const ushort* kh = kb_ + (size_t)bh * 2048 * 64;
    const ushort* vh = vtb + (size_t)bh * 64 * 2048;
    const float* bt = bias_tab + h * 2048;
    const int q0 = qb * 64;

    int crow[2], cj[2];
    #pragma unroll
    for (int i = 0; i < 2; i++) {
        int c = (i * 4 + w) * 64 + lane;
        crow[i] = c >> 3;
        cj[i] = (c & 7) ^ (crow[i] & 7);                  // 3-bit XOR swizzle
    }

    auto stageKV = [&](int buf, int j64) {
        int k0 = j64 * 64;
        #pragma unroll
        for (int i = 0; i < 2; i++) {
            gload16(kh + (size_t)(k0 + crow[i]) * 64 + cj[i] * 8, &KV[buf][0][(i * 4 + w) * 512]);
            gload16(vh + (size_t)crow[i] * 2048 + k0 + cj[i] * 8, &KV[buf][1][(i * 4 + w) * 512]);
        }
    };

    // Q direct global->reg: lane (g,c16) of wave w needs Q[q0+w*16+c16][kk*32+g*8 ..+8)
    const int qrow = q0 + w * 16 + c16;
    bf16x8 qf[2];
    #pragma unroll
    for (int kk = 0; kk < 2; kk++)
        qf[kk] = *(const bf16x8*)(qh + (size_t)qrow * 64 + kk * 32 + g * 8);

    stageKV(0, 0);
    __syncthreads();

    float m_run = -1e30f, l_run = 0.f;
    f32x4 o[4];
    #pragma unroll
    for (int ni = 0; ni < 4; ni++) o[ni] = (f32x4){0.f, 0.f, 0.f, 0.f};
    const float bias_far = bt[128];                       // bucket 31 (all rel >= 91)

    for (int j64 = 0; j64 <= qb; j64++) {
        const int cur = j64 & 1;
        if (j64 < qb) stageKV(cur ^ 1, j64 + 1);          // overlapped with this iter's compute
        const ushort* Ks = KV[cur][0];
        const ushort* Vs = KV[cur][1];
        const int k0 = j64 * 64;

        // S^T = K * Q^T
        f32x4 s[4];
        #pragma unroll
        for (int f = 0; f < 4; f++) s[f] = (f32x4){0.f, 0.f, 0.f, 0.f};
        __builtin_amdgcn_s_setprio(1);
        #pragma unroll
        for (int kk = 0; kk < 2; kk++) {
            #pragma unroll
            for (int f = 0; f < 4; f++) {
                int row = f * 16 + c16;
                bf16x8 a = *(const bf16x8*)(Ks + row * 64 + (((kk * 4 + g) ^ (row & 7)) * 8));
                s[f] = MFMA16(a, qf[kk], s[f]);
            }
        }
        __builtin_amdgcn_s_setprio(0);

        // online softmax; lane holds S[kpos = k0+f*16+g*4+r][qrow]
        const bool near = (qb - j64) < 3;
        const bool diag = (j64 == qb);
        float p[4][4];
        float mt = -1e30f;
        #pragma unroll
        for (int f = 0; f < 4; f++) {
            #pragma unroll
            for (int r = 0; r < 4; r++) {
                int kpos = k0 + f * 16 + g * 4 + r;
                int rel = qrow - kpos;
                float lg;
                if (diag && rel < 0) lg = -1e30f;          // causal mask
                else {
                    float bias = near ? bt[rel] : bias_far;
                    lg = s[f][r] * 0.125f + bias;
                }
                p[f][r] = lg;
                mt = fmaxf(mt, lg);
            }
        }
        mt = fmaxf(mt, __shfl_xor(mt, 16));
        mt = fmaxf(mt, __shfl_xor(mt, 32));
        float m_new = fmaxf(m_run, mt);
        float alpha = __expf(m_run - m_new);
        float lt = 0.f;
        #pragma unroll
        for (int f = 0; f < 4; f++)
            #pragma unroll
            for (int r = 0; r < 4; r++) {
                float e = __expf(p[f][r] - m_new);
                p[f][r] = e;
                lt += e;
            }
        lt += __shfl_xor(lt, 16);
        lt += __shfl_xor(lt, 32);
        l_run = l_run * alpha + lt;
        m_run = m_new;
        #pragma unroll
        for (int ni = 0; ni < 4; ni++) {
            o[ni][0] *= alpha; o[ni][1] *= alpha; o[ni][2] *= alpha; o[ni][3] *= alpha;
        }

        // P -> per-wave LDS (bf16), re-read as B-operand frags (wave-private, no barrier)
        #pragma unroll
        for (int f = 0; f < 4; f++) {
            ushort4 pk;
            pk.x = f2bf_rne(p[f][0]); pk.y = f2bf_rne(p[f][1]);
            pk.z = f2bf_rne(p[f][2]); pk.w = f2bf_rne(p[f][3]);
            *(ushort4*)(&Ps[w][c16 * 72 + f * 16 + g * 4]) = pk;
        }
        __builtin_amdgcn_s_setprio(1);
        #pragma unroll
        for (int kk = 0; kk < 2; kk++) {
            bf16x8 pf = *(const bf16x8*)(&Ps[w][c16 * 72 + kk * 32 + g * 8]);
            #pragma unroll
            for (int ni = 0; ni < 4; ni++) {
                int row = ni * 16 + c16;
                bf16x8 av = *(const bf16x8*)(Vs + row * 64 + (((kk * 4 + g) ^ (row & 7)) * 8));
                o[ni] = MFMA16(av, pf, o[ni]);            // O^T[d][q]
            }
        }
        __builtin_amdgcn_s_setprio(0);
        __syncthreads();   // drains staged next-tile loads + protects cur for next overwrite
    }

    // normalize + write [B,T,H*D] bf16
    float inv = 1.f / l_run;
    size_t base = ((size_t)(b * 2048 + qrow)) * 1024 + h * 64;
    #pragma unroll
    for (int ni = 0; ni < 4; ni++) {
        ushort4 pk;
        pk.x = f2bf_rne(o[ni][0] * inv); pk.y = f2bf_rne(o[ni][1] * inv);
        pk.z = f2bf_rne(o[ni][2] * inv); pk.w = f2bf_rne(o[ni][3] * inv);
        *(ushort4*)(ob + base + ni * 16 + g * 4) = pk;
    }
}

// ---------------- launch ----------------
extern "C" void kernel_launch(void* const* d_in, const int* in_sizes, int n_in,
                              void* d_out, int out_size, void* d_ws, size_t ws_size,
                              hipStream_t stream) {
    const float* x       = (const float*)d_in[0];
    const float* Wq      = (const float*)d_in[1];
    const float* Wk      = (const float*)d_in[2];
    const float* Wv      = (const float*)d_in[3];
    const float* Wo      = (const float*)d_in[4];
    const float* rel_emb = (const float*)d_in[5];

    char* ws = (char*)d_ws;
    ushort* xbf = (ushort*)(ws);                       // 8 MB  [4096][1024]
    ushort* wqb = (ushort*)(ws + (8u  << 20));         // 2 MB each, contiguous after x
    ushort* wkb = (ushort*)(ws + (10u << 20));
    ushort* wvb = (ushort*)(ws + (12u << 20));
    ushort* wob = (ushort*)(ws + (14u << 20));
    ushort* qbf = (ushort*)(ws + (16u << 20));         // 8 MB  [B,H,T,D]
    ushort* kbf = (ushort*)(ws + (24u << 20));         // 8 MB  [B,H,T,D]
    ushort* vtb = (ushort*)(ws + (32u << 20));         // 8 MB  [B,H,D,T]
    ushort* obf = (ushort*)(ws + (40u << 20));         // 8 MB  [4096][1024]
    float*  btab = (float*)(ws + (48u << 20));         // 128 KB [16][2048]

    cvt_all<<<8192, 256, 0, stream>>>(x, Wq, Wk, Wv, Wo, xbf);
    build_bias<<<128, 256, 0, stream>>>(rel_emb, btab);

    gemm_bt<0><<<dim3(32, 24), 256, 0, stream>>>(xbf, wqb, wkb, wvb, qbf, kbf, vtb, nullptr);
    attn_kernel<<<dim3(32, 32), 256, 0, stream>>>(qbf, kbf, vtb, btab, obf);
    gemm_bt<1><<<dim3(64, 8), 256, 0, stream>>>(obf, wob, nullptr, nullptr,
                                                nullptr, nullptr, nullptr, (float*)d_out);
}

// Round 5
// 190.493 us; speedup vs baseline: 1.1058x; 1.1058x over previous
//
#include <hip/hip_runtime.h>
#include <hip/hip_bf16.h>
#include <stdint.h>

// B=2, T=2048, E=1024, H=16, D=64. q=x@Wq^T etc., T5 bias, causal softmax, out=(PV)@Wo^T.

typedef __attribute__((ext_vector_type(8))) short bf16x8;   // 8 bf16 = 4 VGPR (MFMA A/B frag)
typedef __attribute__((ext_vector_type(4))) float f32x4;    // MFMA C/D frag

#define MFMA16(a, b, c) __builtin_amdgcn_mfma_f32_16x16x32_bf16((a), (b), (c), 0, 0, 0)

typedef __attribute__((address_space(1))) void gvoid_t;
typedef __attribute__((address_space(3))) void lvoid_t;

// async global->LDS, 16B/lane; LDS dest is wave-uniform base + lane*16
__device__ __forceinline__ void gload16(const void* g, void* l) {
    __builtin_amdgcn_global_load_lds((gvoid_t*)g, (lvoid_t*)l, 16, 0, 0);
}

__device__ __forceinline__ ushort f2bf_rne(float f) {
    union { float f; uint32_t u; } v; v.f = f;
    uint32_t u = v.u;
    return (ushort)((u + 0x7FFFu + ((u >> 16) & 1u)) >> 16);
}

// ---------------- fused fp32->bf16: x (4M) + Wq/Wk/Wv/Wo (1M each) -> ws[0..8M) ----------
__global__ void cvt_all(const float* __restrict__ x,
                        const float* __restrict__ wq, const float* __restrict__ wk,
                        const float* __restrict__ wv, const float* __restrict__ wo,
                        ushort* __restrict__ out) {
    int i = (blockIdx.x * 256 + threadIdx.x) * 4;           // [0, 8M)
    int sel = i >> 20;
    const float* src; int off;
    if (sel < 4) { src = x; off = i; }
    else {
        src = (sel == 4) ? wq : (sel == 5) ? wk : (sel == 6) ? wv : wo;
        off = i & 1048575;
    }
    float4 f = *(const float4*)(src + off);
    ushort4 o;
    o.x = f2bf_rne(f.x); o.y = f2bf_rne(f.y);
    o.z = f2bf_rne(f.z); o.w = f2bf_rne(f.w);
    *(ushort4*)(out + i) = o;
}

// ---------------- T5 bias table: bias_tab[h][rel], rel in [0,2048) ----------------
// exact integer thresholds: bucket t>=n iff rel >= {8,12,16,23,32,46,64,91}[n]
__global__ void build_bias(const float* __restrict__ rel_emb, float* __restrict__ bias_tab) {
    int idx = blockIdx.x * 256 + threadIdx.x;       // 16*2048
    int h = idx >> 11, rel = idx & 2047;
    int bucket;
    if (rel == 0) bucket = 0;
    else if (rel < 8) bucket = 16 + rel;
    else {
        int t;
        if      (rel >= 91) t = 7;
        else if (rel >= 64) t = 6;
        else if (rel >= 46) t = 5;
        else if (rel >= 32) t = 4;
        else if (rel >= 23) t = 3;
        else if (rel >= 16) t = 2;
        else if (rel >= 12) t = 1;
        else                t = 0;
        bucket = 24 + t;
    }
    bias_tab[idx] = rel_emb[bucket * 16 + h];
}

// ---------------- GEMM: C[M][N] = A[M][1024] * W[N][1024]^T (bf16 in, fp32 acc) ----------
// Double-buffered LDS, 1 barrier/K-step (prefetch next tile before compute).
// MODE 0: BM=128, fused QKV -> q (pre-scaled 0.125),k [B,H,T,D] bf16, V^T [B,H,D,T] bf16
// MODE 1: BM=64 (512 blocks = 2/CU), out-proj -> fp32 d_out
template<int MODE>
__global__ __launch_bounds__(256, MODE == 0 ? 3 : 4) void gemm_bt(
    const ushort* __restrict__ A,
    const ushort* __restrict__ W0, const ushort* __restrict__ W1, const ushort* __restrict__ W2,
    ushort* __restrict__ outq, ushort* __restrict__ outk, ushort* __restrict__ outvt,
    float* __restrict__ outf)
{
    constexpr int BM  = (MODE == 0) ? 128 : 64;
    constexpr int ACH = BM / 64;                    // A chunk-sets per lane (2 or 1)
    constexpr int MI  = (MODE == 0) ? 4 : 2;        // row frags per wave
    __shared__ __align__(16) ushort lsA[2][BM * 32];
    __shared__ __align__(16) ushort lsB[2][128 * 32];
    const int tid = threadIdx.x;
    const int lane = tid & 63, w = tid >> 6;
    const int g = lane >> 4, c16 = lane & 15;
    const int m0 = blockIdx.x * BM;
    const int wm = w >> 1, wn = w & 1;

    const ushort* W;
    int n0, widx = 0;
    if (MODE == 0) {
        widx = blockIdx.y >> 3;
        W = (widx == 0) ? W0 : (widx == 1) ? W1 : W2;
        n0 = (blockIdx.y & 7) * 128;
    } else {
        W = W0;
        n0 = blockIdx.y * 128;
    }

    f32x4 acc[MI][4];
    #pragma unroll
    for (int i = 0; i < MI; i++)
        #pragma unroll
        for (int j = 0; j < 4; j++) acc[i][j] = (f32x4){0.f, 0.f, 0.f, 0.f};

    // staging chunk assignment; XOR swizzle (involution on both sides)
    int acrow[ACH], acj[ACH], bcrow[2], bcj[2];
    #pragma unroll
    for (int i = 0; i < ACH; i++) {
        int c = (i * 4 + w) * 64 + lane;
        acrow[i] = c >> 2; acj[i] = (c & 3) ^ ((acrow[i] >> 1) & 3);
    }
    #pragma unroll
    for (int i = 0; i < 2; i++) {
        int c = (i * 4 + w) * 64 + lane;
        bcrow[i] = c >> 2; bcj[i] = (c & 3) ^ ((bcrow[i] >> 1) & 3);
    }

    auto stage = [&](int buf, int kt) {
        #pragma unroll
        for (int i = 0; i < ACH; i++)
            gload16(A + (size_t)(m0 + acrow[i]) * 1024 + kt + acj[i] * 8,
                    &lsA[buf][(i * 4 + w) * 512]);
        #pragma unroll
        for (int i = 0; i < 2; i++)
            gload16(W + (size_t)(n0 + bcrow[i]) * 1024 + kt + bcj[i] * 8,
                    &lsB[buf][(i * 4 + w) * 512]);
    };

    stage(0, 0);
    __syncthreads();

    for (int it = 0; it < 32; ++it) {
        const int cur = it & 1;
        if (it < 31) stage(cur ^ 1, (it + 1) * 32);   // overlapped with compute below
        bf16x8 af[MI], bfv[4];
        #pragma unroll
        for (int mi = 0; mi < MI; mi++) {
            int row = wm * (16 * MI) + mi * 16 + c16;
            af[mi] = *(const bf16x8*)(&lsA[cur][row * 32 + ((g ^ ((row >> 1) & 3)) * 8)]);
        }
        #pragma unroll
        for (int ni = 0; ni < 4; ni++) {
            int row = wn * 64 + ni * 16 + c16;
            bfv[ni] = *(const bf16x8*)(&lsB[cur][row * 32 + ((g ^ ((row >> 1) & 3)) * 8)]);
        }
        #pragma unroll
        for (int mi = 0; mi < MI; mi++)
            #pragma unroll
            for (int ni = 0; ni < 4; ni++)
                acc[mi][ni] = MFMA16(af[mi], bfv[ni], acc[mi][ni]);
        __syncthreads();   // drains vmcnt (next-tile loads) + syncs readers
    }

    // epilogue. C/D frag: col = lane&15, row = g*4 + r (m89-verified)
    const float qs = (MODE == 0 && 0 == (blockIdx.y >> 3)) ? 0.125f : 1.0f;  // fold QK scale into Q
    #pragma unroll
    for (int mi = 0; mi < MI; mi++) {
        #pragma unroll
        for (int ni = 0; ni < 4; ni++) {
            int mg = m0 + wm * (16 * MI) + mi * 16 + g * 4;
            if (MODE == 0) {
                int f = n0 + wn * 64 + ni * 16 + c16;     // feature in [0,1024)
                int h = f >> 6, d = f & 63;
                if (widx < 2) {
                    ushort* dst = (widx == 0) ? outq : outk;
                    #pragma unroll
                    for (int r = 0; r < 4; r++) {
                        int m = mg + r, b = m >> 11, t = m & 2047;
                        dst[((b * 16 + h) * 2048 + t) * 64 + d] = f2bf_rne(acc[mi][ni][r] * qs);
                    }
                } else {
                    int b = mg >> 11, t = mg & 2047;      // 4 rows stay in one b
                    ushort4 pk;
                    pk.x = f2bf_rne(acc[mi][ni][0]); pk.y = f2bf_rne(acc[mi][ni][1]);
                    pk.z = f2bf_rne(acc[mi][ni][2]); pk.w = f2bf_rne(acc[mi][ni][3]);
                    *(ushort4*)(outvt + ((size_t)(b * 16 + h) * 64 + d) * 2048 + t) = pk;
                }
            } else {
                int ng = n0 + wn * 64 + ni * 16 + c16;
                #pragma unroll
                for (int r = 0; r < 4; r++) {
                    int m = mg + r;
                    outf[(size_t)m * 1024 + ng] = acc[mi][ni][r];
                }
            }
        }
    }
}

// ---------------- Flash attention (causal + T5 bias), single-buffer KV, Q in regs ------
// 64 q-rows/block, 4 waves x 16 rows; 25.6 KB LDS -> 4 blocks/CU (grid 1024 co-resident;
// latency-bound regime: TLP from co-resident blocks is the latency hider, r4 post-mortem).
// Swapped QK^T: S^T = mfma(K, Q); softmax lane-local. PV: O^T = mfma(V^T, P^T).
__global__ __launch_bounds__(256, 4) void attn_kernel(
    const ushort* __restrict__ qb_, const ushort* __restrict__ kb_,
    const ushort* __restrict__ vtb, const float* __restrict__ bias_tab,
    ushort* __restrict__ ob)
{
    __shared__ __align__(16) ushort Ks[64 * 64];
    __shared__ __align__(16) ushort Vs[64 * 64];          // V^T tile: [d][kpos]
    __shared__ __align__(16) ushort Ps[4][16 * 72];       // per-wave P, padded rows

    const int tid = threadIdx.x, lane = tid & 63, w = tid >> 6;
    const int g = lane >> 4, c16 = lane & 15;
    const int bh = blockIdx.y;
    const int qb = (blockIdx.x + bh) & 31;                // work-balance swizzle
    const int b = bh >> 4, h = bh & 15;

    const ushort* qh = qb_ + (size_t)bh * 2048 * 64;
    const ushort* kh = kb_ + (size_t)bh * 2048 * 64;
    const ushort* vh = vtb + (size_t)bh * 64 * 2048;
    const float* bt = bias_tab + h * 2048;
    const int q0 = qb * 64;

    int crow[2], cj[2];
    #pragma unroll
    for (int i = 0; i < 2; i++) {
        int c = (i * 4 + w) * 64 + lane;
        crow[i] = c >> 3;
        cj[i] = (c & 7) ^ (crow[i] & 7);                  // 3-bit XOR swizzle
    }

    // Q direct global->reg (L2-hot, Q pre-scaled by 0.125 at GEMM epilogue)
    const int qrow = q0 + w * 16 + c16;
    bf16x8 qf[2];
    #pragma unroll
    for (int kk = 0; kk < 2; kk++)
        qf[kk] = *(const bf16x8*)(qh + (size_t)qrow * 64 + kk * 32 + g * 8);

    float m_run = -1e30f, l_run = 0.f;
    f32x4 o[4];
    #pragma unroll
    for (int ni = 0; ni < 4; ni++) o[ni] = (f32x4){0.f, 0.f, 0.f, 0.f};
    const float bias_far = bt[128];                       // bucket 31 (all rel >= 91)

    for (int j64 = 0; j64 <= qb; j64++) {
        const int k0 = j64 * 64;
        __syncthreads();                                  // prev readers done before overwrite
        #pragma unroll
        for (int i = 0; i < 2; i++) {
            gload16(kh + (size_t)(k0 + crow[i]) * 64 + cj[i] * 8, Ks + (i * 4 + w) * 512);
            gload16(vh + (size_t)crow[i] * 2048 + k0 + cj[i] * 8, Vs + (i * 4 + w) * 512);
        }
        __syncthreads();

        // S^T = K * Q^T
        f32x4 s[4];
        #pragma unroll
        for (int f = 0; f < 4; f++) s[f] = (f32x4){0.f, 0.f, 0.f, 0.f};
        __builtin_amdgcn_s_setprio(1);
        #pragma unroll
        for (int kk = 0; kk < 2; kk++) {
            #pragma unroll
            for (int f = 0; f < 4; f++) {
                int row = f * 16 + c16;
                bf16x8 a = *(const bf16x8*)(Ks + row * 64 + (((kk * 4 + g) ^ (row & 7)) * 8));
                s[f] = MFMA16(a, qf[kk], s[f]);
            }
        }
        __builtin_amdgcn_s_setprio(0);

        // online softmax; lane holds S[kpos = k0+f*16+g*4+r][qrow] (Q pre-scaled)
        const bool near = (qb - j64) < 3;                 // else all rel>=129 -> bucket 31
        const bool diag = (j64 == qb);
        float p[4][4];
        float m_new, lt = 0.f;
        if (near) {
            float mt = -1e30f;
            #pragma unroll
            for (int f = 0; f < 4; f++)
                #pragma unroll
                for (int r = 0; r < 4; r++) {
                    int kpos = k0 + f * 16 + g * 4 + r;
                    int rel = qrow - kpos;
                    float lg;
                    if (diag && rel < 0) lg = -1e30f;      // causal mask
                    else lg = s[f][r] + bt[rel];
                    p[f][r] = lg;
                    mt = fmaxf(mt, lg);
                }
            mt = fmaxf(mt, __shfl_xor(mt, 16));
            mt = fmaxf(mt, __shfl_xor(mt, 32));
            m_new = fmaxf(m_run, mt);
            #pragma unroll
            for (int f = 0; f < 4; f++)
                #pragma unroll
                for (int r = 0; r < 4; r++) {
                    float e = __expf(p[f][r] - m_new);
                    p[f][r] = e;
                    lt += e;
                }
        } else {
            // far tile: uniform bias -> shift the max instead of per-element add
            float mt = -1e30f;
            #pragma unroll
            for (int f = 0; f < 4; f++)
                #pragma unroll
                for (int r = 0; r < 4; r++) mt = fmaxf(mt, s[f][r]);
            mt = fmaxf(mt, __shfl_xor(mt, 16));
            mt = fmaxf(mt, __shfl_xor(mt, 32));
            m_new = fmaxf(m_run, mt + bias_far);
            float madj = m_new - bias_far;
            #pragma unroll
            for (int f = 0; f < 4; f++)
                #pragma unroll
                for (int r = 0; r < 4; r++) {
                    float e = __expf(s[f][r] - madj);
                    p[f][r] = e;
                    lt += e;
                }
        }
        lt += __shfl_xor(lt, 16);
        lt += __shfl_xor(lt, 32);
        float alpha = __expf(m_run - m_new);
        l_run = l_run * alpha + lt;
        m_run = m_new;
        #pragma unroll
        for (int ni = 0; ni < 4; ni++) {
            o[ni][0] *= alpha; o[ni][1] *= alpha; o[ni][2] *= alpha; o[ni][3] *= alpha;
        }

        // P -> per-wave LDS (bf16), re-read as B-operand frags (wave-private, no barrier)
        #pragma unroll
        for (int f = 0; f < 4; f++) {
            ushort4 pk;
            pk.x = f2bf_rne(p[f][0]); pk.y = f2bf_rne(p[f][1]);
            pk.z = f2bf_rne(p[f][2]); pk.w = f2bf_rne(p[f][3]);
            *(ushort4*)(&Ps[w][c16 * 72 + f * 16 + g * 4]) = pk;
        }
        __builtin_amdgcn_s_setprio(1);
        #pragma unroll
        for (int kk = 0; kk < 2; kk++) {
            bf16x8 pf = *(const bf16x8*)(&Ps[w][c16 * 72 + kk * 32 + g * 8]);
            #pragma unroll
            for (int ni = 0; ni < 4; ni++) {
                int row = ni * 16 + c16;
                bf16x8 av = *(const bf16x8*)(Vs + row * 64 + (((kk * 4 + g) ^ (row & 7)) * 8));
                o[ni] = MFMA16(av, pf, o[ni]);            // O^T[d][q]
            }
        }
        __builtin_amdgcn_s_setprio(0);
    }

    // normalize + write [B,T,H*D] bf16
    float inv = 1.f / l_run;
    size_t base = ((size_t)(b * 2048 + qrow)) * 1024 + h * 64;
    #pragma unroll
    for (int ni = 0; ni < 4; ni++) {
        ushort4 pk;
        pk.x = f2bf_rne(o[ni][0] * inv); pk.y = f2bf_rne(o[ni][1] * inv);
        pk.z = f2bf_rne(o[ni][2] * inv); pk.w = f2bf_rne(o[ni][3] * inv);
        *(ushort4*)(ob + base + ni * 16 + g * 4) = pk;
    }
}

// ---------------- launch ----------------
extern "C" void kernel_launch(void* const* d_in, const int* in_sizes, int n_in,
                              void* d_out, int out_size, void* d_ws, size_t ws_size,
                              hipStream_t stream) {
    const float* x       = (const float*)d_in[0];
    const float* Wq      = (const float*)d_in[1];
    const float* Wk      = (const float*)d_in[2];
    const float* Wv      = (const float*)d_in[3];
    const float* Wo      = (const float*)d_in[4];
    const float* rel_emb = (const float*)d_in[5];

    char* ws = (char*)d_ws;
    ushort* xbf = (ushort*)(ws);                       // 8 MB  [4096][1024]
    ushort* wqb = (ushort*)(ws + (8u  << 20));         // 2 MB each, contiguous after x
    ushort* wkb = (ushort*)(ws + (10u << 20));
    ushort* wvb = (ushort*)(ws + (12u << 20));
    ushort* wob = (ushort*)(ws + (14u << 20));
    ushort* qbf = (ushort*)(ws + (16u << 20));         // 8 MB  [B,H,T,D] (pre-scaled 0.125)
    ushort* kbf = (ushort*)(ws + (24u << 20));         // 8 MB  [B,H,T,D]
    ushort* vtb = (ushort*)(ws + (32u << 20));         // 8 MB  [B,H,D,T]
    ushort* obf = (ushort*)(ws + (40u << 20));         // 8 MB  [4096][1024]
    float*  btab = (float*)(ws + (48u << 20));         // 128 KB [16][2048]

    cvt_all<<<8192, 256, 0, stream>>>(x, Wq, Wk, Wv, Wo, xbf);
    build_bias<<<128, 256, 0, stream>>>(rel_emb, btab);

    gemm_bt<0><<<dim3(32, 24), 256, 0, stream>>>(xbf, wqb, wkb, wvb, qbf, kbf, vtb, nullptr);
    attn_kernel<<<dim3(32, 32), 256, 0, stream>>>(qbf, kbf, vtb, btab, obf);
    gemm_bt<1><<<dim3(64, 8), 256, 0, stream>>>(obf, wob, nullptr, nullptr,
                                                nullptr, nullptr, nullptr, (float*)d_out);
}

// Round 6
// 186.067 us; speedup vs baseline: 1.1321x; 1.0238x over previous
//
#include <hip/hip_runtime.h>
#include <hip/hip_bf16.h>
#include <stdint.h>

// B=2, T=2048, E=1024, H=16, D=64. q=x@Wq^T etc., T5 bias, causal softmax, out=(PV)@Wo^T.

typedef __attribute__((ext_vector_type(8))) short bf16x8;   // 8 bf16 = 4 VGPR (MFMA A/B frag)
typedef __attribute__((ext_vector_type(4))) float f32x4;    // MFMA C/D frag

#define MFMA16(a, b, c) __builtin_amdgcn_mfma_f32_16x16x32_bf16((a), (b), (c), 0, 0, 0)

typedef __attribute__((address_space(1))) void gvoid_t;
typedef __attribute__((address_space(3))) void lvoid_t;

// async global->LDS, 16B/lane; LDS dest is wave-uniform base + lane*16
__device__ __forceinline__ void gload16(const void* g, void* l) {
    __builtin_amdgcn_global_load_lds((gvoid_t*)g, (lvoid_t*)l, 16, 0, 0);
}

__device__ __forceinline__ ushort f2bf_rne(float f) {
    union { float f; uint32_t u; } v; v.f = f;
    uint32_t u = v.u;
    return (ushort)((u + 0x7FFFu + ((u >> 16) & 1u)) >> 16);
}

// ---------------- fused fp32->bf16: x (4M) + Wq/Wk/Wv/Wo (1M each) -> ws[0..8M) ----------
__global__ void cvt_all(const float* __restrict__ x,
                        const float* __restrict__ wq, const float* __restrict__ wk,
                        const float* __restrict__ wv, const float* __restrict__ wo,
                        ushort* __restrict__ out) {
    int i = (blockIdx.x * 256 + threadIdx.x) * 4;           // [0, 8M)
    int sel = i >> 20;
    const float* src; int off;
    if (sel < 4) { src = x; off = i; }
    else {
        src = (sel == 4) ? wq : (sel == 5) ? wk : (sel == 6) ? wv : wo;
        off = i & 1048575;
    }
    float4 f = *(const float4*)(src + off);
    ushort4 o;
    o.x = f2bf_rne(f.x); o.y = f2bf_rne(f.y);
    o.z = f2bf_rne(f.z); o.w = f2bf_rne(f.w);
    *(ushort4*)(out + i) = o;
}

// ---------------- T5 bias table: bias_tab[h][rel], rel in [0,2048) ----------------
// exact integer thresholds: bucket t>=n iff rel >= {8,12,16,23,32,46,64,91}[n]
__global__ void build_bias(const float* __restrict__ rel_emb, float* __restrict__ bias_tab) {
    int idx = blockIdx.x * 256 + threadIdx.x;       // 16*2048
    int h = idx >> 11, rel = idx & 2047;
    int bucket;
    if (rel == 0) bucket = 0;
    else if (rel < 8) bucket = 16 + rel;
    else {
        int t;
        if      (rel >= 91) t = 7;
        else if (rel >= 64) t = 6;
        else if (rel >= 46) t = 5;
        else if (rel >= 32) t = 4;
        else if (rel >= 23) t = 3;
        else if (rel >= 16) t = 2;
        else if (rel >= 12) t = 1;
        else                t = 0;
        bucket = 24 + t;
    }
    bias_tab[idx] = rel_emb[bucket * 16 + h];
}

// ---------------- GEMM: C[M][N] = A[M][1024] * W[N][1024]^T (bf16 in, fp32 acc) ----------
// BK=64 single-buffered, 2 barriers/step, 16 steps: 32 MFMA/wave per barrier-drain
// (2x the BK=32 ratio). Cross-block TLP (3 blocks/CU) hides the drain (m114 mechanism).
// MODE 0: BM=128, fused QKV -> q (pre-scaled 0.125),k [B,H,T,D] bf16, V^T [B,H,D,T] bf16
// MODE 1: BM=64 (512 blocks = 2/CU), out-proj -> fp32 d_out
template<int MODE>
__global__ __launch_bounds__(256, MODE == 0 ? 3 : 2) void gemm_bt(
    const ushort* __restrict__ A,
    const ushort* __restrict__ W0, const ushort* __restrict__ W1, const ushort* __restrict__ W2,
    ushort* __restrict__ outq, ushort* __restrict__ outk, ushort* __restrict__ outvt,
    float* __restrict__ outf)
{
    constexpr int BM  = (MODE == 0) ? 128 : 64;
    constexpr int ACH = BM / 32;                    // A 64-chunk groups (4 or 2)
    constexpr int MI  = (MODE == 0) ? 4 : 2;        // row frags per wave
    __shared__ __align__(16) ushort lsA[BM * 64];   // [row][64] (8 chunks of 8 per row)
    __shared__ __align__(16) ushort lsB[128 * 64];
    const int tid = threadIdx.x;
    const int lane = tid & 63, w = tid >> 6;
    const int g = lane >> 4, c16 = lane & 15;
    const int m0 = blockIdx.x * BM;
    const int wm = w >> 1, wn = w & 1;

    const ushort* W;
    int n0, widx = 0;
    if (MODE == 0) {
        widx = blockIdx.y >> 3;
        W = (widx == 0) ? W0 : (widx == 1) ? W1 : W2;
        n0 = (blockIdx.y & 7) * 128;
    } else {
        W = W0;
        n0 = blockIdx.y * 128;
    }

    f32x4 acc[MI][4];
    #pragma unroll
    for (int i = 0; i < MI; i++)
        #pragma unroll
        for (int j = 0; j < 4; j++) acc[i][j] = (f32x4){0.f, 0.f, 0.f, 0.f};

    // staging chunk assignment; 3-bit XOR swizzle (same involution on write & read)
    int acrow[ACH], acj[ACH], bcrow[4], bcj[4];
    #pragma unroll
    for (int i = 0; i < ACH; i++) {
        int c = (i * 4 + w) * 64 + lane;            // chunk id in [0, BM*8)
        acrow[i] = c >> 3; acj[i] = (c & 7) ^ (acrow[i] & 7);
    }
    #pragma unroll
    for (int i = 0; i < 4; i++) {
        int c = (i * 4 + w) * 64 + lane;            // chunk id in [0, 1024)
        bcrow[i] = c >> 3; bcj[i] = (c & 7) ^ (bcrow[i] & 7);
    }

    for (int kt = 0; kt < 1024; kt += 64) {
        __syncthreads();                            // prev readers done before overwrite
        #pragma unroll
        for (int i = 0; i < ACH; i++)
            gload16(A + (size_t)(m0 + acrow[i]) * 1024 + kt + acj[i] * 8,
                    lsA + (i * 4 + w) * 512);
        #pragma unroll
        for (int i = 0; i < 4; i++)
            gload16(W + (size_t)(n0 + bcrow[i]) * 1024 + kt + bcj[i] * 8,
                    lsB + (i * 4 + w) * 512);
        __syncthreads();                            // drain staging
        #pragma unroll
        for (int kk = 0; kk < 2; kk++) {
            bf16x8 af[MI], bfv[4];
            #pragma unroll
            for (int mi = 0; mi < MI; mi++) {
                int row = wm * (16 * MI) + mi * 16 + c16;
                af[mi] = *(const bf16x8*)(lsA + row * 64 + (((kk * 4 + g) ^ (row & 7)) * 8));
            }
            #pragma unroll
            for (int ni = 0; ni < 4; ni++) {
                int row = wn * 64 + ni * 16 + c16;
                bfv[ni] = *(const bf16x8*)(lsB + row * 64 + (((kk * 4 + g) ^ (row & 7)) * 8));
            }
            #pragma unroll
            for (int mi = 0; mi < MI; mi++)
                #pragma unroll
                for (int ni = 0; ni < 4; ni++)
                    acc[mi][ni] = MFMA16(af[mi], bfv[ni], acc[mi][ni]);
        }
    }

    // epilogue. C/D frag: col = lane&15, row = g*4 + r (m89-verified)
    const float qs = (MODE == 0 && widx == 0) ? 0.125f : 1.0f;   // fold QK scale into Q
    #pragma unroll
    for (int mi = 0; mi < MI; mi++) {
        #pragma unroll
        for (int ni = 0; ni < 4; ni++) {
            int mg = m0 + wm * (16 * MI) + mi * 16 + g * 4;
            if (MODE == 0) {
                int f = n0 + wn * 64 + ni * 16 + c16;     // feature in [0,1024)
                int h = f >> 6, d = f & 63;
                if (widx < 2) {
                    ushort* dst = (widx == 0) ? outq : outk;
                    #pragma unroll
                    for (int r = 0; r < 4; r++) {
                        int m = mg + r, b = m >> 11, t = m & 2047;
                        dst[((b * 16 + h) * 2048 + t) * 64 + d] = f2bf_rne(acc[mi][ni][r] * qs);
                    }
                } else {
                    int b = mg >> 11, t = mg & 2047;      // 4 rows stay in one b
                    ushort4 pk;
                    pk.x = f2bf_rne(acc[mi][ni][0]); pk.y = f2bf_rne(acc[mi][ni][1]);
                    pk.z = f2bf_rne(acc[mi][ni][2]); pk.w = f2bf_rne(acc[mi][ni][3]);
                    *(ushort4*)(outvt + ((size_t)(b * 16 + h) * 64 + d) * 2048 + t) = pk;
                }
            } else {
                int ng = n0 + wn * 64 + ni * 16 + c16;
                #pragma unroll
                for (int r = 0; r < 4; r++) {
                    int m = mg + r;
                    outf[(size_t)m * 1024 + ng] = acc[mi][ni][r];
                }
            }
        }
    }
}

// ---------------- Flash attention (causal + T5 bias), paired q-tiles for balance -------
// Block processes q-tiles {px, 31-px}: exactly 33 K-tile-steps per block, grid 16x32=512
// uniform blocks (2/CU co-resident, zero stochastic tail — r5 post-mortem: makespan was
// set by CUs drawing heavy causal-triangle blocks). 25.6 KB LDS. Swapped QK^T; PV via V^T.
__global__ __launch_bounds__(256, 4) void attn_kernel(
    const ushort* __restrict__ qb_, const ushort* __restrict__ kb_,
    const ushort* __restrict__ vtb, const float* __restrict__ bias_tab,
    ushort* __restrict__ ob)
{
    __shared__ __align__(16) ushort Ks[64 * 64];
    __shared__ __align__(16) ushort Vs[64 * 64];          // V^T tile: [d][kpos]
    __shared__ __align__(16) ushort Ps[4][16 * 72];       // per-wave P, padded rows

    const int tid = threadIdx.x, lane = tid & 63, w = tid >> 6;
    const int g = lane >> 4, c16 = lane & 15;
    const int bh = blockIdx.y;
    const int px = blockIdx.x;                            // pair index 0..15
    const int b = bh >> 4, h = bh & 15;

    const ushort* qh = qb_ + (size_t)bh * 2048 * 64;
    const ushort* kh = kb_ + (size_t)bh * 2048 * 64;
    const ushort* vh = vtb + (size_t)bh * 64 * 2048;
    const float* bt = bias_tab + h * 2048;
    const float bias_far = bt[128];                       // bucket 31 (all rel >= 91)

    int crow[2], cj[2];
    #pragma unroll
    for (int i = 0; i < 2; i++) {
        int c = (i * 4 + w) * 64 + lane;
        crow[i] = c >> 3;
        cj[i] = (c & 7) ^ (crow[i] & 7);                  // 3-bit XOR swizzle
    }

    for (int half = 0; half < 2; half++) {
        const int qb = half ? 31 - px : px;
        const int q0 = qb * 64;
        const int qrow = q0 + w * 16 + c16;

        // Q direct global->reg (L2-hot, Q pre-scaled by 0.125 at GEMM epilogue)
        bf16x8 qf[2];
        #pragma unroll
        for (int kk = 0; kk < 2; kk++)
            qf[kk] = *(const bf16x8*)(qh + (size_t)qrow * 64 + kk * 32 + g * 8);

        float m_run = -1e30f, l_run = 0.f;
        f32x4 o[4];
        #pragma unroll
        for (int ni = 0; ni < 4; ni++) o[ni] = (f32x4){0.f, 0.f, 0.f, 0.f};

        for (int j64 = 0; j64 <= qb; j64++) {
            const int k0 = j64 * 64;
            __syncthreads();                              // prev readers done before overwrite
            #pragma unroll
            for (int i = 0; i < 2; i++) {
                gload16(kh + (size_t)(k0 + crow[i]) * 64 + cj[i] * 8, Ks + (i * 4 + w) * 512);
                gload16(vh + (size_t)crow[i] * 2048 + k0 + cj[i] * 8, Vs + (i * 4 + w) * 512);
            }
            __syncthreads();

            // S^T = K * Q^T
            f32x4 s[4];
            #pragma unroll
            for (int f = 0; f < 4; f++) s[f] = (f32x4){0.f, 0.f, 0.f, 0.f};
            __builtin_amdgcn_s_setprio(1);
            #pragma unroll
            for (int kk = 0; kk < 2; kk++) {
                #pragma unroll
                for (int f = 0; f < 4; f++) {
                    int row = f * 16 + c16;
                    bf16x8 a = *(const bf16x8*)(Ks + row * 64 + (((kk * 4 + g) ^ (row & 7)) * 8));
                    s[f] = MFMA16(a, qf[kk], s[f]);
                }
            }
            __builtin_amdgcn_s_setprio(0);

            // online softmax; lane holds S[kpos = k0+f*16+g*4+r][qrow] (Q pre-scaled)
            const bool near = (qb - j64) < 3;             // else all rel>=129 -> bucket 31
            const bool diag = (j64 == qb);
            float p[4][4];
            float m_new, lt = 0.f;
            if (near) {
                float mt = -1e30f;
                #pragma unroll
                for (int f = 0; f < 4; f++)
                    #pragma unroll
                    for (int r = 0; r < 4; r++) {
                        int kpos = k0 + f * 16 + g * 4 + r;
                        int rel = qrow - kpos;
                        float lg;
                        if (diag && rel < 0) lg = -1e30f;  // causal mask
                        else lg = s[f][r] + bt[rel];
                        p[f][r] = lg;
                        mt = fmaxf(mt, lg);
                    }
                mt = fmaxf(mt, __shfl_xor(mt, 16));
                mt = fmaxf(mt, __shfl_xor(mt, 32));
                m_new = fmaxf(m_run, mt);
                #pragma unroll
                for (int f = 0; f < 4; f++)
                    #pragma unroll
                    for (int r = 0; r < 4; r++) {
                        float e = __expf(p[f][r] - m_new);
                        p[f][r] = e;
                        lt += e;
                    }
            } else {
                // far tile: uniform bias -> shift the max instead of per-element add
                float mt = -1e30f;
                #pragma unroll
                for (int f = 0; f < 4; f++)
                    #pragma unroll
                    for (int r = 0; r < 4; r++) mt = fmaxf(mt, s[f][r]);
                mt = fmaxf(mt, __shfl_xor(mt, 16));
                mt = fmaxf(mt, __shfl_xor(mt, 32));
                m_new = fmaxf(m_run, mt + bias_far);
                float madj = m_new - bias_far;
                #pragma unroll
                for (int f = 0; f < 4; f++)
                    #pragma unroll
                    for (int r = 0; r < 4; r++) {
                        float e = __expf(s[f][r] - madj);
                        p[f][r] = e;
                        lt += e;
                    }
            }
            lt += __shfl_xor(lt, 16);
            lt += __shfl_xor(lt, 32);
            float alpha = __expf(m_run - m_new);
            l_run = l_run * alpha + lt;
            m_run = m_new;
            #pragma unroll
            for (int ni = 0; ni < 4; ni++) {
                o[ni][0] *= alpha; o[ni][1] *= alpha; o[ni][2] *= alpha; o[ni][3] *= alpha;
            }

            // P -> per-wave LDS (bf16), re-read as B-operand frags (wave-private)
            #pragma unroll
            for (int f = 0; f < 4; f++) {
                ushort4 pk;
                pk.x = f2bf_rne(p[f][0]); pk.y = f2bf_rne(p[f][1]);
                pk.z = f2bf_rne(p[f][2]); pk.w = f2bf_rne(p[f][3]);
                *(ushort4*)(&Ps[w][c16 * 72 + f * 16 + g * 4]) = pk;
            }
            __builtin_amdgcn_s_setprio(1);
            #pragma unroll
            for (int kk = 0; kk < 2; kk++) {
                bf16x8 pf = *(const bf16x8*)(&Ps[w][c16 * 72 + kk * 32 + g * 8]);
                #pragma unroll
                for (int ni = 0; ni < 4; ni++) {
                    int row = ni * 16 + c16;
                    bf16x8 av = *(const bf16x8*)(Vs + row * 64 + (((kk * 4 + g) ^ (row & 7)) * 8));
                    o[ni] = MFMA16(av, pf, o[ni]);        // O^T[d][q]
                }
            }
            __builtin_amdgcn_s_setprio(0);
        }

        // normalize + write [B,T,H*D] bf16
        float inv = 1.f / l_run;
        size_t base = ((size_t)(b * 2048 + qrow)) * 1024 + h * 64;
        #pragma unroll
        for (int ni = 0; ni < 4; ni++) {
            ushort4 pk;
            pk.x = f2bf_rne(o[ni][0] * inv); pk.y = f2bf_rne(o[ni][1] * inv);
            pk.z = f2bf_rne(o[ni][2] * inv); pk.w = f2bf_rne(o[ni][3] * inv);
            *(ushort4*)(ob + base + ni * 16 + g * 4) = pk;
        }
    }
}

// ---------------- launch ----------------
extern "C" void kernel_launch(void* const* d_in, const int* in_sizes, int n_in,
                              void* d_out, int out_size, void* d_ws, size_t ws_size,
                              hipStream_t stream) {
    const float* x       = (const float*)d_in[0];
    const float* Wq      = (const float*)d_in[1];
    const float* Wk      = (const float*)d_in[2];
    const float* Wv      = (const float*)d_in[3];
    const float* Wo      = (const float*)d_in[4];
    const float* rel_emb = (const float*)d_in[5];

    char* ws = (char*)d_ws;
    ushort* xbf = (ushort*)(ws);                       // 8 MB  [4096][1024]
    ushort* wqb = (ushort*)(ws + (8u  << 20));         // 2 MB each, contiguous after x
    ushort* wkb = (ushort*)(ws + (10u << 20));
    ushort* wvb = (ushort*)(ws + (12u << 20));
    ushort* wob = (ushort*)(ws + (14u << 20));
    ushort* qbf = (ushort*)(ws + (16u << 20));         // 8 MB  [B,H,T,D] (pre-scaled 0.125)
    ushort* kbf = (ushort*)(ws + (24u << 20));         // 8 MB  [B,H,T,D]
    ushort* vtb = (ushort*)(ws + (32u << 20));         // 8 MB  [B,H,D,T]
    ushort* obf = (ushort*)(ws + (40u << 20));         // 8 MB  [4096][1024]
    float*  btab = (float*)(ws + (48u << 20));         // 128 KB [16][2048]

    cvt_all<<<8192, 256, 0, stream>>>(x, Wq, Wk, Wv, Wo, xbf);
    build_bias<<<128, 256, 0, stream>>>(rel_emb, btab);

    gemm_bt<0><<<dim3(32, 24), 256, 0, stream>>>(xbf, wqb, wkb, wvb, qbf, kbf, vtb, nullptr);
    attn_kernel<<<dim3(16, 32), 256, 0, stream>>>(qbf, kbf, vtb, btab, obf);
    gemm_bt<1><<<dim3(64, 8), 256, 0, stream>>>(obf, wob, nullptr, nullptr,
                                                nullptr, nullptr, nullptr, (float*)d_out);
}

// Round 7
// 179.359 us; speedup vs baseline: 1.1745x; 1.0374x over previous
//
#include <hip/hip_runtime.h>
#include <hip/hip_bf16.h>
#include <stdint.h>

// B=2, T=2048, E=1024, H=16, D=64. q=x@Wq^T etc., T5 bias, causal softmax, out=(PV)@Wo^T.

typedef __attribute__((ext_vector_type(8))) short bf16x8;   // 8 bf16 = 4 VGPR (MFMA A/B frag)
typedef __attribute__((ext_vector_type(4))) float f32x4;    // MFMA C/D frag

#define MFMA16(a, b, c) __builtin_amdgcn_mfma_f32_16x16x32_bf16((a), (b), (c), 0, 0, 0)

typedef __attribute__((address_space(1))) void gvoid_t;
typedef __attribute__((address_space(3))) void lvoid_t;

// async global->LDS, 16B/lane; LDS dest is wave-uniform base + lane*16
__device__ __forceinline__ void gload16(const void* g, void* l) {
    __builtin_amdgcn_global_load_lds((gvoid_t*)g, (lvoid_t*)l, 16, 0, 0);
}

__device__ __forceinline__ ushort f2bf_rne(float f) {
    union { float f; uint32_t u; } v; v.f = f;
    uint32_t u = v.u;
    return (ushort)((u + 0x7FFFu + ((u >> 16) & 1u)) >> 16);
}

// ---------------- fused fp32->bf16: x (4M) + Wq/Wk/Wv/Wo (1M each) -> ws[0..8M) ----------
__global__ void cvt_all(const float* __restrict__ x,
                        const float* __restrict__ wq, const float* __restrict__ wk,
                        const float* __restrict__ wv, const float* __restrict__ wo,
                        ushort* __restrict__ out) {
    int i = (blockIdx.x * 256 + threadIdx.x) * 4;           // [0, 8M)
    int sel = i >> 20;
    const float* src; int off;
    if (sel < 4) { src = x; off = i; }
    else {
        src = (sel == 4) ? wq : (sel == 5) ? wk : (sel == 6) ? wv : wo;
        off = i & 1048575;
    }
    float4 f = *(const float4*)(src + off);
    ushort4 o;
    o.x = f2bf_rne(f.x); o.y = f2bf_rne(f.y);
    o.z = f2bf_rne(f.z); o.w = f2bf_rne(f.w);
    *(ushort4*)(out + i) = o;
}

// ---------------- T5 bias table: bias_tab[h][rel], rel in [0,2048) ----------------
// exact integer thresholds: bucket t>=n iff rel >= {8,12,16,23,32,46,64,91}[n]
__global__ void build_bias(const float* __restrict__ rel_emb, float* __restrict__ bias_tab) {
    int idx = blockIdx.x * 256 + threadIdx.x;       // 16*2048
    int h = idx >> 11, rel = idx & 2047;
    int bucket;
    if (rel == 0) bucket = 0;
    else if (rel < 8) bucket = 16 + rel;
    else {
        int t;
        if      (rel >= 91) t = 7;
        else if (rel >= 64) t = 6;
        else if (rel >= 46) t = 5;
        else if (rel >= 32) t = 4;
        else if (rel >= 23) t = 3;
        else if (rel >= 16) t = 2;
        else if (rel >= 12) t = 1;
        else                t = 0;
        bucket = 24 + t;
    }
    bias_tab[idx] = rel_emb[bucket * 16 + h];
}

// ---------------- GEMM: C[M][N] = A[M][1024] * W[N][1024]^T (bf16 in, fp32 acc) ----------
// BK=64 single-buffered, 2 barriers/step, 16 steps (UNCHANGED from r6 — control while
// attn change is attributed; first GEMM counters expected next round).
// MODE 0: BM=128, fused QKV -> q (pre-scaled 0.125),k [B,H,T,D] bf16, V^T [B,H,D,T] bf16
// MODE 1: BM=64, out-proj -> fp32 d_out
template<int MODE>
__global__ __launch_bounds__(256, MODE == 0 ? 3 : 2) void gemm_bt(
    const ushort* __restrict__ A,
    const ushort* __restrict__ W0, const ushort* __restrict__ W1, const ushort* __restrict__ W2,
    ushort* __restrict__ outq, ushort* __restrict__ outk, ushort* __restrict__ outvt,
    float* __restrict__ outf)
{
    constexpr int BM  = (MODE == 0) ? 128 : 64;
    constexpr int ACH = BM / 32;                    // A 64-chunk groups (4 or 2)
    constexpr int MI  = (MODE == 0) ? 4 : 2;        // row frags per wave
    __shared__ __align__(16) ushort lsA[BM * 64];   // [row][64] (8 chunks of 8 per row)
    __shared__ __align__(16) ushort lsB[128 * 64];
    const int tid = threadIdx.x;
    const int lane = tid & 63, w = tid >> 6;
    const int g = lane >> 4, c16 = lane & 15;
    const int m0 = blockIdx.x * BM;
    const int wm = w >> 1, wn = w & 1;

    const ushort* W;
    int n0, widx = 0;
    if (MODE == 0) {
        widx = blockIdx.y >> 3;
        W = (widx == 0) ? W0 : (widx == 1) ? W1 : W2;
        n0 = (blockIdx.y & 7) * 128;
    } else {
        W = W0;
        n0 = blockIdx.y * 128;
    }

    f32x4 acc[MI][4];
    #pragma unroll
    for (int i = 0; i < MI; i++)
        #pragma unroll
        for (int j = 0; j < 4; j++) acc[i][j] = (f32x4){0.f, 0.f, 0.f, 0.f};

    // staging chunk assignment; 3-bit XOR swizzle (same involution on write & read)
    int acrow[ACH], acj[ACH], bcrow[4], bcj[4];
    #pragma unroll
    for (int i = 0; i < ACH; i++) {
        int c = (i * 4 + w) * 64 + lane;            // chunk id in [0, BM*8)
        acrow[i] = c >> 3; acj[i] = (c & 7) ^ (acrow[i] & 7);
    }
    #pragma unroll
    for (int i = 0; i < 4; i++) {
        int c = (i * 4 + w) * 64 + lane;            // chunk id in [0, 1024)
        bcrow[i] = c >> 3; bcj[i] = (c & 7) ^ (bcrow[i] & 7);
    }

    for (int kt = 0; kt < 1024; kt += 64) {
        __syncthreads();                            // prev readers done before overwrite
        #pragma unroll
        for (int i = 0; i < ACH; i++)
            gload16(A + (size_t)(m0 + acrow[i]) * 1024 + kt + acj[i] * 8,
                    lsA + (i * 4 + w) * 512);
        #pragma unroll
        for (int i = 0; i < 4; i++)
            gload16(W + (size_t)(n0 + bcrow[i]) * 1024 + kt + bcj[i] * 8,
                    lsB + (i * 4 + w) * 512);
        __syncthreads();                            // drain staging
        #pragma unroll
        for (int kk = 0; kk < 2; kk++) {
            bf16x8 af[MI], bfv[4];
            #pragma unroll
            for (int mi = 0; mi < MI; mi++) {
                int row = wm * (16 * MI) + mi * 16 + c16;
                af[mi] = *(const bf16x8*)(lsA + row * 64 + (((kk * 4 + g) ^ (row & 7)) * 8));
            }
            #pragma unroll
            for (int ni = 0; ni < 4; ni++) {
                int row = wn * 64 + ni * 16 + c16;
                bfv[ni] = *(const bf16x8*)(lsB + row * 64 + (((kk * 4 + g) ^ (row & 7)) * 8));
            }
            #pragma unroll
            for (int mi = 0; mi < MI; mi++)
                #pragma unroll
                for (int ni = 0; ni < 4; ni++)
                    acc[mi][ni] = MFMA16(af[mi], bfv[ni], acc[mi][ni]);
        }
    }

    // epilogue. C/D frag: col = lane&15, row = g*4 + r (m89-verified)
    const float qs = (MODE == 0 && widx == 0) ? 0.125f : 1.0f;   // fold QK scale into Q
    #pragma unroll
    for (int mi = 0; mi < MI; mi++) {
        #pragma unroll
        for (int ni = 0; ni < 4; ni++) {
            int mg = m0 + wm * (16 * MI) + mi * 16 + g * 4;
            if (MODE == 0) {
                int f = n0 + wn * 64 + ni * 16 + c16;     // feature in [0,1024)
                int h = f >> 6, d = f & 63;
                if (widx < 2) {
                    ushort* dst = (widx == 0) ? outq : outk;
                    #pragma unroll
                    for (int r = 0; r < 4; r++) {
                        int m = mg + r, b = m >> 11, t = m & 2047;
                        dst[((b * 16 + h) * 2048 + t) * 64 + d] = f2bf_rne(acc[mi][ni][r] * qs);
                    }
                } else {
                    int b = mg >> 11, t = mg & 2047;      // 4 rows stay in one b
                    ushort4 pk;
                    pk.x = f2bf_rne(acc[mi][ni][0]); pk.y = f2bf_rne(acc[mi][ni][1]);
                    pk.z = f2bf_rne(acc[mi][ni][2]); pk.w = f2bf_rne(acc[mi][ni][3]);
                    *(ushort4*)(outvt + ((size_t)(b * 16 + h) * 64 + d) * 2048 + t) = pk;
                }
            } else {
                int ng = n0 + wn * 64 + ni * 16 + c16;
                #pragma unroll
                for (int r = 0; r < 4; r++) {
                    int m = mg + r;
                    outf[(size_t)m * 1024 + ng] = acc[mi][ni][r];
                }
            }
        }
    }
}

// ---------------- Flash attention (causal + T5 bias) -----------------------------------
// 1024 blocks (4/CU, all co-resident, 16 waves/CU TLP — the latency hider, r4/r6 lesson).
// Work balance WITHOUT pairing: sequential dispatch places blocks p and p+256 on the same
// CU; rounds j>>5 = 0..3 map qb = px, 31-px, px, 31-px -> every CU sums to 66 K-steps.
// XCD-clustered bh: p&7 selects XCD (round-robin dispatch), bh = 4*(p&7) + round -> each
// bh's K/V prefix is read within one XCD's L2, one temporal round (FETCH was 5x unique).
// Mapping is a bijection onto (bh, qb): correctness never depends on dispatch assumptions.
__global__ __launch_bounds__(256, 4) void attn_kernel(
    const ushort* __restrict__ qb_, const ushort* __restrict__ kb_,
    const ushort* __restrict__ vtb, const float* __restrict__ bias_tab,
    ushort* __restrict__ ob)
{
    __shared__ __align__(16) ushort Ks[64 * 64];
    __shared__ __align__(16) ushort Vs[64 * 64];          // V^T tile: [d][kpos]
    __shared__ __align__(16) ushort Ps[4][16 * 72];       // per-wave P, padded rows

    const int tid = threadIdx.x, lane = tid & 63, w = tid >> 6;
    const int g = lane >> 4, c16 = lane & 15;
    const int p = blockIdx.x;
    const int xcd = p & 7, j = p >> 3;
    const int round = j >> 5, px = j & 31;
    const int bh = (xcd << 2) | round;                    // [0,32)
    const int qb = (round & 1) ? (31 - px) : px;
    const int b = bh >> 4, h = bh & 15;

    const ushort* qh = qb_ + (size_t)bh * 2048 * 64;
    const ushort* kh = kb_ + (size_t)bh * 2048 * 64;
    const ushort* vh = vtb + (size_t)bh * 64 * 2048;
    const float* bt = bias_tab + h * 2048;
    const float bias_far = bt[128];                       // bucket 31 (all rel >= 91)
    const int q0 = qb * 64;
    const int qrow = q0 + w * 16 + c16;

    int crow[2], cj[2];
    #pragma unroll
    for (int i = 0; i < 2; i++) {
        int c = (i * 4 + w) * 64 + lane;
        crow[i] = c >> 3;
        cj[i] = (c & 7) ^ (crow[i] & 7);                  // 3-bit XOR swizzle
    }

    // Q direct global->reg (L2-hot, Q pre-scaled by 0.125 at GEMM epilogue)
    bf16x8 qf[2];
    #pragma unroll
    for (int kk = 0; kk < 2; kk++)
        qf[kk] = *(const bf16x8*)(qh + (size_t)qrow * 64 + kk * 32 + g * 8);

    float m_run = -1e30f, l_run = 0.f;
    f32x4 o[4];
    #pragma unroll
    for (int ni = 0; ni < 4; ni++) o[ni] = (f32x4){0.f, 0.f, 0.f, 0.f};

    for (int j64 = 0; j64 <= qb; j64++) {
        const int k0 = j64 * 64;
        __syncthreads();                                  // prev readers done before overwrite
        #pragma unroll
        for (int i = 0; i < 2; i++) {
            gload16(kh + (size_t)(k0 + crow[i]) * 64 + cj[i] * 8, Ks + (i * 4 + w) * 512);
            gload16(vh + (size_t)crow[i] * 2048 + k0 + cj[i] * 8, Vs + (i * 4 + w) * 512);
        }
        __syncthreads();

        // S^T = K * Q^T
        f32x4 s[4];
        #pragma unroll
        for (int f = 0; f < 4; f++) s[f] = (f32x4){0.f, 0.f, 0.f, 0.f};
        __builtin_amdgcn_s_setprio(1);
        #pragma unroll
        for (int kk = 0; kk < 2; kk++) {
            #pragma unroll
            for (int f = 0; f < 4; f++) {
                int row = f * 16 + c16;
                bf16x8 a = *(const bf16x8*)(Ks + row * 64 + (((kk * 4 + g) ^ (row & 7)) * 8));
                s[f] = MFMA16(a, qf[kk], s[f]);
            }
        }
        __builtin_amdgcn_s_setprio(0);

        // online softmax; lane holds S[kpos = k0+f*16+g*4+r][qrow] (Q pre-scaled)
        const bool near = (qb - j64) < 3;                 // else all rel>=129 -> bucket 31
        const bool diag = (j64 == qb);
        float p4[4][4];
        float m_new, lt = 0.f;
        if (near) {
            float mt = -1e30f;
            #pragma unroll
            for (int f = 0; f < 4; f++)
                #pragma unroll
                for (int r = 0; r < 4; r++) {
                    int kpos = k0 + f * 16 + g * 4 + r;
                    int rel = qrow - kpos;
                    float lg;
                    if (diag && rel < 0) lg = -1e30f;      // causal mask
                    else lg = s[f][r] + bt[rel];
                    p4[f][r] = lg;
                    mt = fmaxf(mt, lg);
                }
            mt = fmaxf(mt, __shfl_xor(mt, 16));
            mt = fmaxf(mt, __shfl_xor(mt, 32));
            m_new = fmaxf(m_run, mt);
            #pragma unroll
            for (int f = 0; f < 4; f++)
                #pragma unroll
                for (int r = 0; r < 4; r++) {
                    float e = __expf(p4[f][r] - m_new);
                    p4[f][r] = e;
                    lt += e;
                }
        } else {
            // far tile: uniform bias -> shift the max instead of per-element add
            float mt = -1e30f;
            #pragma unroll
            for (int f = 0; f < 4; f++)
                #pragma unroll
                for (int r = 0; r < 4; r++) mt = fmaxf(mt, s[f][r]);
            mt = fmaxf(mt, __shfl_xor(mt, 16));
            mt = fmaxf(mt, __shfl_xor(mt, 32));
            m_new = fmaxf(m_run, mt + bias_far);
            float madj = m_new - bias_far;
            #pragma unroll
            for (int f = 0; f < 4; f++)
                #pragma unroll
                for (int r = 0; r < 4; r++) {
                    float e = __expf(s[f][r] - madj);
                    p4[f][r] = e;
                    lt += e;
                }
        }
        lt += __shfl_xor(lt, 16);
        lt += __shfl_xor(lt, 32);
        float alpha = __expf(m_run - m_new);
        l_run = l_run * alpha + lt;
        m_run = m_new;
        #pragma unroll
        for (int ni = 0; ni < 4; ni++) {
            o[ni][0] *= alpha; o[ni][1] *= alpha; o[ni][2] *= alpha; o[ni][3] *= alpha;
        }

        // P -> per-wave LDS (bf16), re-read as B-operand frags (wave-private)
        #pragma unroll
        for (int f = 0; f < 4; f++) {
            ushort4 pk;
            pk.x = f2bf_rne(p4[f][0]); pk.y = f2bf_rne(p4[f][1]);
            pk.z = f2bf_rne(p4[f][2]); pk.w = f2bf_rne(p4[f][3]);
            *(ushort4*)(&Ps[w][c16 * 72 + f * 16 + g * 4]) = pk;
        }
        __builtin_amdgcn_s_setprio(1);
        #pragma unroll
        for (int kk = 0; kk < 2; kk++) {
            bf16x8 pf = *(const bf16x8*)(&Ps[w][c16 * 72 + kk * 32 + g * 8]);
            #pragma unroll
            for (int ni = 0; ni < 4; ni++) {
                int row = ni * 16 + c16;
                bf16x8 av = *(const bf16x8*)(Vs + row * 64 + (((kk * 4 + g) ^ (row & 7)) * 8));
                o[ni] = MFMA16(av, pf, o[ni]);            // O^T[d][q]
            }
        }
        __builtin_amdgcn_s_setprio(0);
    }

    // normalize + write [B,T,H*D] bf16
    float inv = 1.f / l_run;
    size_t base = ((size_t)(b * 2048 + qrow)) * 1024 + h * 64;
    #pragma unroll
    for (int ni = 0; ni < 4; ni++) {
        ushort4 pk;
        pk.x = f2bf_rne(o[ni][0] * inv); pk.y = f2bf_rne(o[ni][1] * inv);
        pk.z = f2bf_rne(o[ni][2] * inv); pk.w = f2bf_rne(o[ni][3] * inv);
        *(ushort4*)(ob + base + ni * 16 + g * 4) = pk;
    }
}

// ---------------- launch ----------------
extern "C" void kernel_launch(void* const* d_in, const int* in_sizes, int n_in,
                              void* d_out, int out_size, void* d_ws, size_t ws_size,
                              hipStream_t stream) {
    const float* x       = (const float*)d_in[0];
    const float* Wq      = (const float*)d_in[1];
    const float* Wk      = (const float*)d_in[2];
    const float* Wv      = (const float*)d_in[3];
    const float* Wo      = (const float*)d_in[4];
    const float* rel_emb = (const float*)d_in[5];

    char* ws = (char*)d_ws;
    ushort* xbf = (ushort*)(ws);                       // 8 MB  [4096][1024]
    ushort* wqb = (ushort*)(ws + (8u  << 20));         // 2 MB each, contiguous after x
    ushort* wkb = (ushort*)(ws + (10u << 20));
    ushort* wvb = (ushort*)(ws + (12u << 20));
    ushort* wob = (ushort*)(ws + (14u << 20));
    ushort* qbf = (ushort*)(ws + (16u << 20));         // 8 MB  [B,H,T,D] (pre-scaled 0.125)
    ushort* kbf = (ushort*)(ws + (24u << 20));         // 8 MB  [B,H,T,D]
    ushort* vtb = (ushort*)(ws + (32u << 20));         // 8 MB  [B,H,D,T]
    ushort* obf = (ushort*)(ws + (40u << 20));         // 8 MB  [4096][1024]
    float*  btab = (float*)(ws + (48u << 20));         // 128 KB [16][2048]

    cvt_all<<<8192, 256, 0, stream>>>(x, Wq, Wk, Wv, Wo, xbf);
    build_bias<<<128, 256, 0, stream>>>(rel_emb, btab);

    gemm_bt<0><<<dim3(32, 24), 256, 0, stream>>>(xbf, wqb, wkb, wvb, qbf, kbf, vtb, nullptr);
    attn_kernel<<<1024, 256, 0, stream>>>(qbf, kbf, vtb, btab, obf);
    gemm_bt<1><<<dim3(64, 8), 256, 0, stream>>>(obf, wob, nullptr, nullptr,
                                                nullptr, nullptr, nullptr, (float*)d_out);
}